// Round 3
// baseline (615.784 us; speedup 1.0000x reference)
//
#include <hip/hip_runtime.h>
#include <hip/hip_bf16.h>
#include <stdint.h>

// Problem constants (GumbelVectorQuantizer): B=32,T=1536,C=768,G=2,Vg=160
#define BT_TOK   49152      // B*T
#define C_DIM    768
#define NVARS    320        // G*Vg
#define VG       160
#define NGROUPS  2

// ---------------------------------------------------------------------------
// bf16 helpers (RNE, branch-free; inputs are finite)
// ---------------------------------------------------------------------------
__device__ __forceinline__ unsigned short bf16_rne(float f) {
    union { float f; uint32_t u; } v; v.f = f;
    uint32_t u = v.u + 0x7FFFu + ((v.u >> 16) & 1u);
    return (unsigned short)(u >> 16);
}
__device__ __forceinline__ float bf16_to_f(unsigned short h) {
    union { uint32_t u; float f; } v; v.u = ((uint32_t)h) << 16;
    return v.f;
}

typedef __attribute__((ext_vector_type(8))) short bf16x8;   // 8 bf16 = 4 VGPRs
typedef __attribute__((ext_vector_type(4))) float f32x4;

#define GLOBAL_AS __attribute__((address_space(1)))
#define LDS_AS    __attribute__((address_space(3)))
__device__ __forceinline__ void gl2lds16(const void* g, void* l) {
    // width=16 global->LDS DMA; LDS dest is wave-uniform base + lane*16
    __builtin_amdgcn_global_load_lds((const GLOBAL_AS void*)g, (LDS_AS void*)l, 16, 0, 0);
}

// ---------------------------------------------------------------------------
// Prepass: transpose (K x N fp32) -> (N x K) bf16 hi/lo. Tiny matrices.
// grid = (ceil(K/256), N)
// ---------------------------------------------------------------------------
__global__ __launch_bounds__(256)
void transpose_split(const float* __restrict__ in, unsigned short* __restrict__ hi,
                     unsigned short* __restrict__ lo, int K, int N) {
    int k = blockIdx.x * 256 + threadIdx.x;
    int n = blockIdx.y;
    if (k >= K) return;
    float f = in[(size_t)k * N + n];
    unsigned short h = bf16_rne(f);
    hi[(size_t)n * K + k] = h;
    lo[(size_t)n * K + k] = bf16_rne(f - bf16_to_f(h));
}

// ===========================================================================
// FUSED GEMM1 + gumbel-softmax (R4).
// logits = X(fp32) @ (Whi+Wlo) + b computed via in-register bf16 hi/lo split
// of A (ds_write into swizzled LDS; fp32 x is the same byte count as the old
// xhi+xlo, so no extra traffic) and 3-MFMA split product.  B (W^T, ~1 MB) is
// L2-resident, staged via global_load_lds.  Double-buffered 2-phase K-loop
// with T14 split on A (load early, convert+ds_write after the MFMA phase).
// Epilogue: acc -> LDS f32 (stride 321), block-wide gumbel-softmax per
// (row, group), writes probs (fp32 out), codes.  Logits NEVER touch HBM.
// Instantiated <64, 320, 1, 5> (320 thr, grid (1,768) = 3 even rounds).
// ===========================================================================
template<int BM, int BN, int WM, int WN>
__global__ __launch_bounds__(WM*WN*64, 2)
void gemm1_softmax_fused(const float* __restrict__ X,
                         const unsigned short* __restrict__ Bthi,
                         const unsigned short* __restrict__ Btlo,
                         const float* __restrict__ bias,
                         const float* __restrict__ gumbel,
                         float* __restrict__ probs,
                         float* __restrict__ codes,
                         int M, int N, int K)
{
    constexpr int NW = WM * WN;
    constexpr int ACH    = BM * 4;          // 8-elem A chunks per K-step
    constexpr int nIterB = (BN * 4) / 64;
    constexpr int ABYTES = BM * 32 * 2;     // one A sub-buffer (hi or lo)
    constexpr int BBYTES = BN * 32 * 2;
    constexpr int BUFBYTES = 2 * ABYTES + 2 * BBYTES;

    extern __shared__ __align__(16) char smem[];   // 2 * BUFBYTES

    const int tid  = threadIdx.x;
    const int lane = tid & 63;
    const int wid  = tid >> 6;
    const int wm   = wid % WM;
    const int wn   = wid / WM;
    const int m0   = blockIdx.y * BM;
    const int n0   = blockIdx.x * BN;

    const int r15 = lane & 15;
    const int q   = lane >> 4;

    // A chunk owned by this thread (row, logical chunk) -> swizzled slot
    const int arow  = tid >> 2;
    const int ac    = tid & 3;
    const int aslot = ac ^ ((arow >> 1) & 3);
    const float* aptr = X + (size_t)(m0 + arow) * K + ac * 8;
    const bool adoes = (tid < ACH);

    f32x4 acc[4][4];
#pragma unroll
    for (int i = 0; i < 4; ++i)
#pragma unroll
        for (int j = 0; j < 4; ++j) {
            f32x4 z = {0.f, 0.f, 0.f, 0.f};
            acc[i][j] = z;
        }

    auto issueB = [&](int buf, int k0) {
        char* base = smem + buf * BUFBYTES + 2 * ABYTES;
        for (int i = wid; i < nIterB; i += NW) {
            int slot = i * 64 + lane;
            int row  = slot >> 2, cs = slot & 3;
            int c    = cs ^ ((row >> 1) & 3);
            size_t goff = (size_t)(n0 + row) * K + k0 + c * 8;
            gl2lds16(Bthi + goff, base + i * 1024);
            gl2lds16(Btlo + goff, base + BBYTES + i * 1024);
        }
    };

    float4 av0, av1;
    auto loadA = [&](int k0) {
        if (adoes) {
            av0 = *(const float4*)(aptr + k0);
            av1 = *(const float4*)(aptr + k0 + 4);
        }
    };
    auto writeA = [&](int buf) {
        if (adoes) {
            char* base = smem + buf * BUFBYTES;
            union { unsigned short u[8]; bf16x8 v; } h, l;
            float f[8] = {av0.x, av0.y, av0.z, av0.w, av1.x, av1.y, av1.z, av1.w};
#pragma unroll
            for (int j = 0; j < 8; ++j) {
                h.u[j] = bf16_rne(f[j]);
                l.u[j] = bf16_rne(f[j] - bf16_to_f(h.u[j]));
            }
            *(bf16x8*)(base + arow * 64 + aslot * 16)          = h.v;
            *(bf16x8*)(base + ABYTES + arow * 64 + aslot * 16) = l.v;
        }
    };

    const int NT = K / 32;
    loadA(0);
    issueB(0, 0);
    writeA(0);
    __syncthreads();   // prologue drain (vmcnt + lgkm)

    int cur = 0;
    for (int t = 0; t < NT; ++t) {
        // phase 1: issue next-tile A loads (to regs) + B global_load_lds
        if (t + 1 < NT) { loadA((t + 1) * 32); issueB(cur ^ 1, (t + 1) * 32); }

        // phase 2: compute current tile
        const unsigned short* sAh = (const unsigned short*)(smem + cur * BUFBYTES);
        const unsigned short* sAl = (const unsigned short*)(smem + cur * BUFBYTES + ABYTES);
        const unsigned short* sBh = (const unsigned short*)(smem + cur * BUFBYTES + 2 * ABYTES);
        const unsigned short* sBl = (const unsigned short*)(smem + cur * BUFBYTES + 2 * ABYTES + BBYTES);

        bf16x8 ah[4], al[4], bh[4], bl[4];
#pragma unroll
        for (int mi = 0; mi < 4; ++mi) {
            int row = wm * 64 + mi * 16 + r15;
            int off = row * 32 + ((q ^ ((row >> 1) & 3)) * 8);
            ah[mi] = *(const bf16x8*)&sAh[off];
            al[mi] = *(const bf16x8*)&sAl[off];
        }
#pragma unroll
        for (int ni = 0; ni < 4; ++ni) {
            int row = wn * 64 + ni * 16 + r15;
            int off = row * 32 + ((q ^ ((row >> 1) & 3)) * 8);
            bh[ni] = *(const bf16x8*)&sBh[off];
            bl[ni] = *(const bf16x8*)&sBl[off];
        }

#pragma unroll
        for (int mi = 0; mi < 4; ++mi)
#pragma unroll
            for (int ni = 0; ni < 4; ++ni) {
                acc[mi][ni] = __builtin_amdgcn_mfma_f32_16x16x32_bf16(ah[mi], bh[ni], acc[mi][ni], 0, 0, 0);
                acc[mi][ni] = __builtin_amdgcn_mfma_f32_16x16x32_bf16(ah[mi], bl[ni], acc[mi][ni], 0, 0, 0);
                acc[mi][ni] = __builtin_amdgcn_mfma_f32_16x16x32_bf16(al[mi], bh[ni], acc[mi][ni], 0, 0, 0);
            }

        // phase 3 (T14 write-late): convert + ds_write next A tile
        if (t + 1 < NT) writeA(cur ^ 1);

        __syncthreads();   // single barrier per K-step
        cur ^= 1;
    }

    // ---- fused epilogue: logits -> LDS f32, block-wide gumbel-softmax ----
    // (reuses smem; last barrier above guarantees all ds_reads done)
    float* sL = (float*)smem;
    constexpr int LSTR = BN + 1;   // pad to break bank conflicts
#pragma unroll
    for (int ni = 0; ni < 4; ++ni) {
        int col = wn * 64 + ni * 16 + r15;
        float bv = bias[n0 + col];
#pragma unroll
        for (int mi = 0; mi < 4; ++mi) {
            int rbase = wm * 64 + mi * 16 + q * 4;
#pragma unroll
            for (int rr = 0; rr < 4; ++rr)
                sL[(rbase + rr) * LSTR + col] = acc[mi][ni][rr] + bv;
        }
    }
    __syncthreads();

    // 2*BM row-groups (row, group), one wave each; 160 vals -> 3 per lane
    for (int rg = wid; rg < 2 * BM; rg += NW) {
        const int r = rg >> 1, g = rg & 1;
        const float* gsrc = gumbel + (size_t)(m0 + r) * NVARS + g * VG;
        const float* lrow = sL + r * LSTR + g * VG;
        const bool  has2 = (lane < VG - 128);   // lanes 0..31

        float y0 = (lrow[lane]       + gsrc[lane])       * 0.5f;   // /TEMP
        float y1 = (lrow[lane + 64]  + gsrc[lane + 64])  * 0.5f;
        float y2 = has2 ? (lrow[lane + 128] + gsrc[lane + 128]) * 0.5f
                        : -3.402823466e+38f;

        float mx = fmaxf(fmaxf(y0, y1), y2);
#pragma unroll
        for (int off = 32; off > 0; off >>= 1)
            mx = fmaxf(mx, __shfl_xor(mx, off, 64));

        float e0 = expf(y0 - mx);
        float e1 = expf(y1 - mx);
        float e2 = has2 ? expf(y2 - mx) : 0.f;
        float s  = e0 + e1 + e2;
#pragma unroll
        for (int off = 32; off > 0; off >>= 1)
            s += __shfl_xor(s, off, 64);
        const float inv = 1.0f / s;

        float* prow = probs + (size_t)(m0 + r) * NVARS + g * VG;
        prow[lane]      = e0 * inv;
        prow[lane + 64] = e1 * inv;
        if (has2) prow[lane + 128] = e2 * inv;

        // argmax over y (monotone-equivalent to argmax over probs),
        // first-occurrence tie-break — identical to previous rounds
        float bvv = y0; int bii = lane;
        if (y1 > bvv) { bvv = y1; bii = lane + 64; }
        if (has2 && y2 > bvv) { bvv = y2; bii = lane + 128; }
#pragma unroll
        for (int off = 32; off > 0; off >>= 1) {
            float ov = __shfl_xor(bvv, off, 64);
            int   oi = __shfl_xor(bii, off, 64);
            if (ov > bvv || (ov == bvv && oi < bii)) { bvv = ov; bii = oi; }
        }
        if (lane == 0) codes[(size_t)(m0 + r) * NGROUPS + g] = (float)bii;
    }
}

// ===========================================================================
// FUSED GEMM2 (R4): quantized = probs(fp32) @ (CBhi+CBlo).
// A = probs read fp32, split hi/lo in registers (same bytes as old phi/plo),
// ds_write into swizzled LDS.  Convert happens BEFORE the MFMA phase so the
// staging registers die early (768-thread block => 170-VGPR cap).  B
// (codebook^T, ~1 MB) staged via global_load_lds.  Double-buffered 2-phase.
// Instantiated <128, 384, 2, 6> (768 thr, grid (2,384) = 3 even rounds).
// ===========================================================================
template<int BM, int BN, int WM, int WN>
__global__ __launch_bounds__(WM*WN*64, (WM*WN+3)/4)
void gemm2_fused(const float* __restrict__ P,
                 const unsigned short* __restrict__ Bthi,
                 const unsigned short* __restrict__ Btlo,
                 float* __restrict__ C,
                 int M, int N, int K)
{
    constexpr int NW = WM * WN;
    constexpr int ACH    = BM * 4;
    constexpr int nIterB = (BN * 4) / 64;
    constexpr int ABYTES = BM * 32 * 2;
    constexpr int BBYTES = BN * 32 * 2;
    constexpr int BUFBYTES = 2 * ABYTES + 2 * BBYTES;

    extern __shared__ __align__(16) char smem[];   // 2 * BUFBYTES

    const int tid  = threadIdx.x;
    const int lane = tid & 63;
    const int wid  = tid >> 6;
    const int wm   = wid % WM;
    const int wn   = wid / WM;
    const int m0   = blockIdx.y * BM;
    const int n0   = blockIdx.x * BN;

    const int r15 = lane & 15;
    const int q   = lane >> 4;

    const int arow  = tid >> 2;
    const int ac    = tid & 3;
    const int aslot = ac ^ ((arow >> 1) & 3);
    const float* aptr = P + (size_t)(m0 + arow) * K + ac * 8;
    const bool adoes = (tid < ACH);

    f32x4 acc[4][4];
#pragma unroll
    for (int i = 0; i < 4; ++i)
#pragma unroll
        for (int j = 0; j < 4; ++j) {
            f32x4 z = {0.f, 0.f, 0.f, 0.f};
            acc[i][j] = z;
        }

    auto issueB = [&](int buf, int k0) {
        char* base = smem + buf * BUFBYTES + 2 * ABYTES;
        for (int i = wid; i < nIterB; i += NW) {
            int slot = i * 64 + lane;
            int row  = slot >> 2, cs = slot & 3;
            int c    = cs ^ ((row >> 1) & 3);
            size_t goff = (size_t)(n0 + row) * K + k0 + c * 8;
            gl2lds16(Bthi + goff, base + i * 1024);
            gl2lds16(Btlo + goff, base + BBYTES + i * 1024);
        }
    };

    auto stageA = [&](int buf, int k0) {
        if (adoes) {
            float4 av0 = *(const float4*)(aptr + k0);
            float4 av1 = *(const float4*)(aptr + k0 + 4);
            char* base = smem + buf * BUFBYTES;
            union { unsigned short u[8]; bf16x8 v; } h, l;
            float f[8] = {av0.x, av0.y, av0.z, av0.w, av1.x, av1.y, av1.z, av1.w};
#pragma unroll
            for (int j = 0; j < 8; ++j) {
                h.u[j] = bf16_rne(f[j]);
                l.u[j] = bf16_rne(f[j] - bf16_to_f(h.u[j]));
            }
            *(bf16x8*)(base + arow * 64 + aslot * 16)          = h.v;
            *(bf16x8*)(base + ABYTES + arow * 64 + aslot * 16) = l.v;
        }
    };

    const int NT = K / 32;
    issueB(0, 0);
    stageA(0, 0);
    __syncthreads();

    int cur = 0;
    for (int t = 0; t < NT; ++t) {
        if (t + 1 < NT) { issueB(cur ^ 1, (t + 1) * 32); stageA(cur ^ 1, (t + 1) * 32); }

        const unsigned short* sAh = (const unsigned short*)(smem + cur * BUFBYTES);
        const unsigned short* sAl = (const unsigned short*)(smem + cur * BUFBYTES + ABYTES);
        const unsigned short* sBh = (const unsigned short*)(smem + cur * BUFBYTES + 2 * ABYTES);
        const unsigned short* sBl = (const unsigned short*)(smem + cur * BUFBYTES + 2 * ABYTES + BBYTES);

        bf16x8 ah[4], al[4], bh[4], bl[4];
#pragma unroll
        for (int mi = 0; mi < 4; ++mi) {
            int row = wm * 64 + mi * 16 + r15;
            int off = row * 32 + ((q ^ ((row >> 1) & 3)) * 8);
            ah[mi] = *(const bf16x8*)&sAh[off];
            al[mi] = *(const bf16x8*)&sAl[off];
        }
#pragma unroll
        for (int ni = 0; ni < 4; ++ni) {
            int row = wn * 64 + ni * 16 + r15;
            int off = row * 32 + ((q ^ ((row >> 1) & 3)) * 8);
            bh[ni] = *(const bf16x8*)&sBh[off];
            bl[ni] = *(const bf16x8*)&sBl[off];
        }

#pragma unroll
        for (int mi = 0; mi < 4; ++mi)
#pragma unroll
            for (int ni = 0; ni < 4; ++ni) {
                acc[mi][ni] = __builtin_amdgcn_mfma_f32_16x16x32_bf16(ah[mi], bh[ni], acc[mi][ni], 0, 0, 0);
                acc[mi][ni] = __builtin_amdgcn_mfma_f32_16x16x32_bf16(ah[mi], bl[ni], acc[mi][ni], 0, 0, 0);
                acc[mi][ni] = __builtin_amdgcn_mfma_f32_16x16x32_bf16(al[mi], bh[ni], acc[mi][ni], 0, 0, 0);
            }

        __syncthreads();
        cur ^= 1;
    }

    // epilogue: C/D layout col=lane&15, row=quad*4+reg (m89/m91-verified)
#pragma unroll
    for (int ni = 0; ni < 4; ++ni) {
        int col = n0 + wn * 64 + ni * 16 + r15;
#pragma unroll
        for (int mi = 0; mi < 4; ++mi) {
            int rbase = m0 + wm * 64 + mi * 16 + q * 4;
#pragma unroll
            for (int rr = 0; rr < 4; ++rr)
                C[(size_t)(rbase + rr) * N + col] = acc[mi][ni][rr];
        }
    }
}

// ---------------------------------------------------------------------------
// Fallback kernels (known-good fp32 path) if ws is too small.
// ---------------------------------------------------------------------------
__global__ __launch_bounds__(256)
void gumbel_softmax_kernel(float* __restrict__ logits_probs,
                           const float* __restrict__ gumbel,
                           float* __restrict__ codes,
                           unsigned short* __restrict__ phi,
                           unsigned short* __restrict__ plo)
{
    const int wid  = (int)((blockIdx.x * (size_t)blockDim.x + threadIdx.x) >> 6);
    const int lane = threadIdx.x & 63;
    if (wid >= BT_TOK * NGROUPS) return;

    float* base        = logits_probs + (size_t)wid * VG;
    const float* gbase = gumbel       + (size_t)wid * VG;

    const float NEG = -3.402823466e+38f;
    float y[3];
    float mx = NEG;
#pragma unroll
    for (int i = 0; i < 3; ++i) {
        int v = lane + i * 64;
        float val = NEG;
        if (v < VG) val = (base[v] + gbase[v]) * 0.5f;
        y[i] = val;
        mx = fmaxf(mx, val);
    }
#pragma unroll
    for (int off = 32; off > 0; off >>= 1)
        mx = fmaxf(mx, __shfl_xor(mx, off, 64));

    float e[3];
    float s = 0.f;
#pragma unroll
    for (int i = 0; i < 3; ++i) {
        int v = lane + i * 64;
        e[i] = (v < VG) ? expf(y[i] - mx) : 0.f;
        s += e[i];
    }
#pragma unroll
    for (int off = 32; off > 0; off >>= 1)
        s += __shfl_xor(s, off, 64);
    const float inv = 1.0f / s;

#pragma unroll
    for (int i = 0; i < 3; ++i) {
        int v = lane + i * 64;
        if (v < VG) {
            float p = e[i] * inv;
            base[v] = p;
            if (phi) {
                unsigned short h = bf16_rne(p);
                phi[(size_t)wid * VG + v] = h;
                plo[(size_t)wid * VG + v] = bf16_rne(p - bf16_to_f(h));
            }
        }
    }

    float bv = y[0];
    int   bi = lane;
#pragma unroll
    for (int i = 1; i < 3; ++i) {
        int v = lane + i * 64;
        if (v < VG && y[i] > bv) { bv = y[i]; bi = v; }
    }
#pragma unroll
    for (int off = 32; off > 0; off >>= 1) {
        float ov = __shfl_xor(bv, off, 64);
        int   oi = __shfl_xor(bi, off, 64);
        if (ov > bv || (ov == bv && oi < bi)) { bv = ov; bi = oi; }
    }
    if (lane == 0) codes[wid] = (float)bi;
}

__global__ __launch_bounds__(256)
void sgemm64(const float* __restrict__ A, const float* __restrict__ B,
             const float* __restrict__ bias, float* __restrict__ C,
             int M, int N, int K)
{
    const int tid = threadIdx.x;
    const int n0  = blockIdx.x * 64;
    const int m0  = blockIdx.y * 64;

    __shared__ float As[16][64 + 4];
    __shared__ float Bs[16][64];

    const int a_row = tid >> 2;
    const int a_k   = (tid & 3) * 4;
    const int b_row = tid >> 4;
    const int b_col = (tid & 15) * 4;
    const int tx = tid & 15;
    const int ty = tid >> 4;

    float acc[4][4] = {};

    for (int k0 = 0; k0 < K; k0 += 16) {
        float4 av = *(const float4*)(A + (size_t)(m0 + a_row) * K + k0 + a_k);
        float4 bv = *(const float4*)(B + (size_t)(k0 + b_row) * N + n0 + b_col);
        __syncthreads();
        As[a_k + 0][a_row] = av.x;
        As[a_k + 1][a_row] = av.y;
        As[a_k + 2][a_row] = av.z;
        As[a_k + 3][a_row] = av.w;
        *(float4*)&Bs[b_row][b_col] = bv;
        __syncthreads();
#pragma unroll
        for (int k = 0; k < 16; ++k) {
            float4 a4 = *(const float4*)&As[k][ty * 4];
            float4 b4 = *(const float4*)&Bs[k][tx * 4];
            const float a[4] = {a4.x, a4.y, a4.z, a4.w};
            const float b[4] = {b4.x, b4.y, b4.z, b4.w};
#pragma unroll
            for (int r = 0; r < 4; ++r)
#pragma unroll
                for (int c = 0; c < 4; ++c)
                    acc[r][c] = fmaf(a[r], b[c], acc[r][c]);
        }
    }

    float4 bs = make_float4(0.f, 0.f, 0.f, 0.f);
    if (bias) bs = *(const float4*)(bias + n0 + tx * 4);
#pragma unroll
    for (int r = 0; r < 4; ++r) {
        float4 o;
        o.x = acc[r][0] + bs.x;
        o.y = acc[r][1] + bs.y;
        o.z = acc[r][2] + bs.z;
        o.w = acc[r][3] + bs.w;
        *(float4*)(C + (size_t)(m0 + ty * 4 + r) * N + n0 + tx * 4) = o;
    }
}

// ---------------------------------------------------------------------------
extern "C" void kernel_launch(void* const* d_in, const int* in_sizes, int n_in,
                              void* d_out, int out_size, void* d_ws, size_t ws_size,
                              hipStream_t stream) {
    const float* x        = (const float*)d_in[0];   // (BT, 768)
    const float* gumbel   = (const float*)d_in[1];   // (BT, 320)
    const float* W_proj   = (const float*)d_in[2];   // (768, 320)
    const float* b_proj   = (const float*)d_in[3];   // (320,)
    const float* codebook = (const float*)d_in[4];   // (320, 768)

    float* quantized = (float*)d_out;
    float* codes     = quantized + (size_t)BT_TOK * C_DIM;
    float* probs     = codes + (size_t)BT_TOK * NGROUPS;

    // workspace: only the two transposed weight matrices (hi/lo) now
    const size_t SZ_W  = (size_t)C_DIM * NVARS * 2;    // 491,520 per buffer
    const size_t need  = 4 * SZ_W;                     // ~2 MB

    // dynamic-LDS sizes
    constexpr int SH1 = 2 * (2 * (64 * 32 * 2)  + 2 * (320 * 32 * 2));   //  98304 B
    constexpr int SH2 = 2 * (2 * (128 * 32 * 2) + 2 * (384 * 32 * 2));   // 131072 B

    if (ws_size >= need) {
        static bool s_init = false;
        if (!s_init) {
            hipFuncSetAttribute(reinterpret_cast<const void*>(&gemm1_softmax_fused<64, 320, 1, 5>),
                                hipFuncAttributeMaxDynamicSharedMemorySize, SH1);
            hipFuncSetAttribute(reinterpret_cast<const void*>(&gemm2_fused<128, 384, 2, 6>),
                                hipFuncAttributeMaxDynamicSharedMemorySize, SH2);
            s_init = true;
        }

        char* ws = (char*)d_ws;
        unsigned short* wthi = (unsigned short*)(ws);
        unsigned short* wtlo = (unsigned short*)(ws + SZ_W);
        unsigned short* cthi = (unsigned short*)(ws + 2 * SZ_W);
        unsigned short* ctlo = (unsigned short*)(ws + 3 * SZ_W);

        // tiny weight prepasses
        transpose_split<<<dim3((C_DIM + 255) / 256, NVARS), 256, 0, stream>>>(
            W_proj, wthi, wtlo, C_DIM, NVARS);
        transpose_split<<<dim3((NVARS + 255) / 256, C_DIM), 256, 0, stream>>>(
            codebook, cthi, ctlo, NVARS, C_DIM);

        // fused GEMM1 + softmax: x -> probs, codes (logits stay on-chip)
        gemm1_softmax_fused<64, 320, 1, 5><<<dim3(1, BT_TOK / 64), 320, SH1, stream>>>(
            x, wthi, wtlo, b_proj, gumbel, probs, codes, BT_TOK, NVARS, C_DIM);

        // fused GEMM2: probs (fp32, split in-register) @ codebook -> quantized
        gemm2_fused<128, 384, 2, 6><<<dim3(C_DIM / 384, BT_TOK / 128), 768, SH2, stream>>>(
            probs, cthi, ctlo, quantized, BT_TOK, C_DIM, NVARS);
    } else {
        // fallback: known-good fp32 path
        dim3 g1(NVARS / 64, BT_TOK / 64);
        sgemm64<<<g1, 256, 0, stream>>>(x, W_proj, b_proj, probs, BT_TOK, NVARS, C_DIM);
        gumbel_softmax_kernel<<<BT_TOK * NGROUPS / 4, 256, 0, stream>>>(
            probs, gumbel, codes, nullptr, nullptr);
        dim3 g2(C_DIM / 64, BT_TOK / 64);
        sgemm64<<<g2, 256, 0, stream>>>(probs, codebook, nullptr, quantized, BT_TOK, C_DIM, NVARS);
    }
}

// Round 4
// 610.901 us; speedup vs baseline: 1.0080x; 1.0080x over previous
//
#include <hip/hip_runtime.h>
#include <hip/hip_bf16.h>
#include <stdint.h>

// Problem constants (GumbelVectorQuantizer): B=32,T=1536,C=768,G=2,Vg=160
#define BT_TOK   49152      // B*T
#define C_DIM    768
#define NVARS    320        // G*Vg
#define VG       160
#define NGROUPS  2

// ---------------------------------------------------------------------------
// bf16 helpers (RNE, branch-free; inputs are finite)
// ---------------------------------------------------------------------------
__device__ __forceinline__ unsigned short bf16_rne(float f) {
    union { float f; uint32_t u; } v; v.f = f;
    uint32_t u = v.u + 0x7FFFu + ((v.u >> 16) & 1u);
    return (unsigned short)(u >> 16);
}
__device__ __forceinline__ float bf16_to_f(unsigned short h) {
    union { uint32_t u; float f; } v; v.u = ((uint32_t)h) << 16;
    return v.f;
}

typedef __attribute__((ext_vector_type(8))) short bf16x8;   // 8 bf16 = 4 VGPRs
typedef __attribute__((ext_vector_type(4))) float f32x4;

#define GLOBAL_AS __attribute__((address_space(1)))
#define LDS_AS    __attribute__((address_space(3)))
__device__ __forceinline__ void gl2lds16(const void* g, void* l) {
    // width=16 global->LDS DMA; LDS dest is wave-uniform base + lane*16
    __builtin_amdgcn_global_load_lds((const GLOBAL_AS void*)g, (LDS_AS void*)l, 16, 0, 0);
}

// Counted-vmcnt workgroup barrier (T4): drain lgkm + all but `leave2?2:0`
// newest VMEM ops, then raw s_barrier.  The 2 left in flight are the 2-deep
// A prefetch loads (the NEWEST issues of the iteration).  Branch is
// wave-uniform; all waves reach the single s_barrier.
__device__ __forceinline__ void wg_barrier_leave(bool leave2) {
    if (leave2) asm volatile("s_waitcnt vmcnt(2) lgkmcnt(0)" ::: "memory");
    else        asm volatile("s_waitcnt vmcnt(0) lgkmcnt(0)" ::: "memory");
    __builtin_amdgcn_s_barrier();
    asm volatile("" ::: "memory");
    __builtin_amdgcn_sched_barrier(0);
}

// ---------------------------------------------------------------------------
// Prepass: transpose (K x N fp32) -> (N x K) bf16 hi/lo. Tiny matrices.
// grid = (ceil(K/256), N)
// ---------------------------------------------------------------------------
__global__ __launch_bounds__(256)
void transpose_split(const float* __restrict__ in, unsigned short* __restrict__ hi,
                     unsigned short* __restrict__ lo, int K, int N) {
    int k = blockIdx.x * 256 + threadIdx.x;
    int n = blockIdx.y;
    if (k >= K) return;
    float f = in[(size_t)k * N + n];
    unsigned short h = bf16_rne(f);
    hi[(size_t)n * K + k] = h;
    lo[(size_t)n * K + k] = bf16_rne(f - bf16_to_f(h));
}

// ===========================================================================
// FUSED GEMM1 + gumbel-softmax (R5: counted-vmcnt pipeline).
// logits = X(fp32) @ (Whi+Wlo) + b, in-register hi/lo split of A, 3-MFMA
// split product.  K-loop pipeline (per iter t):
//   issueB(t+1 DMA) -> loadA(t+2 -> regs) -> compute(t) -> writeA(t+1 from
//   regs loaded one full iteration ago) -> barrier leaving the 2 A-loads
//   in flight (vmcnt(2)).
// A-load latency (~900cy HBM) is covered by ~2 compute phases; B DMAs
// (L2-hot, ~1MB matrix) are drained at each barrier after ~450cy of cover.
// Epilogue: logits -> LDS f32 (stride BN+1), block-wide gumbel-softmax with
// software-pipelined gumbel prefetch; writes probs + codes.  Logits never
// touch HBM.  Instantiated <64, 320, 1, 5> (320 thr, grid (1,768)).
// ===========================================================================
template<int BM, int BN, int WM, int WN>
__global__ __launch_bounds__(WM*WN*64, 2)
void gemm1_softmax_fused(const float* __restrict__ X,
                         const unsigned short* __restrict__ Bthi,
                         const unsigned short* __restrict__ Btlo,
                         const float* __restrict__ bias,
                         const float* __restrict__ gumbel,
                         float* __restrict__ probs,
                         float* __restrict__ codes,
                         int M, int N, int K)
{
    constexpr int NW = WM * WN;
    constexpr int ACH    = BM * 4;          // 8-elem A chunks per K-step
    constexpr int AW     = ACH / 64;        // # waves that stage A
    constexpr int nIterB = (BN * 4) / 64;
    constexpr int ABYTES = BM * 32 * 2;     // one A sub-buffer (hi or lo)
    constexpr int BBYTES = BN * 32 * 2;
    constexpr int BUFBYTES = 2 * ABYTES + 2 * BBYTES;

    extern __shared__ __align__(16) char smem[];   // 2 * BUFBYTES

    const int tid  = threadIdx.x;
    const int lane = tid & 63;
    const int wid  = tid >> 6;
    const int wm   = wid % WM;
    const int wn   = wid / WM;
    const int m0   = blockIdx.y * BM;
    const int n0   = blockIdx.x * BN;

    const int r15 = lane & 15;
    const int q   = lane >> 4;

    // A chunk owned by this thread (row, logical chunk) -> swizzled slot
    const int arow  = tid >> 2;
    const int ac    = tid & 3;
    const int aslot = ac ^ ((arow >> 1) & 3);
    const float* aptr = X + (size_t)(m0 + arow) * K + ac * 8;
    const bool adoes = (tid < ACH);        // wave-uniform (ACH multiple of 64)
    const bool awave = (wid < AW);

    f32x4 acc[4][4];
#pragma unroll
    for (int i = 0; i < 4; ++i)
#pragma unroll
        for (int j = 0; j < 4; ++j) {
            f32x4 z = {0.f, 0.f, 0.f, 0.f};
            acc[i][j] = z;
        }

    auto issueB = [&](int buf, int k0) {
        char* base = smem + buf * BUFBYTES + 2 * ABYTES;
        for (int i = wid; i < nIterB; i += NW) {
            int slot = i * 64 + lane;
            int row  = slot >> 2, cs = slot & 3;
            int c    = cs ^ ((row >> 1) & 3);
            size_t goff = (size_t)(n0 + row) * K + k0 + c * 8;
            gl2lds16(Bthi + goff, base + i * 1024);
            gl2lds16(Btlo + goff, base + BBYTES + i * 1024);
        }
    };
    auto loadA = [&](float4& v0, float4& v1, int k0) {
        if (adoes) {
            v0 = *(const float4*)(aptr + k0);
            v1 = *(const float4*)(aptr + k0 + 4);
        }
    };
    auto writeA = [&](int buf, float4 v0, float4 v1) {
        if (adoes) {
            char* base = smem + buf * BUFBYTES;
            union { unsigned short u[8]; bf16x8 v; } h, l;
            float f[8] = {v0.x, v0.y, v0.z, v0.w, v1.x, v1.y, v1.z, v1.w};
#pragma unroll
            for (int j = 0; j < 8; ++j) {
                h.u[j] = bf16_rne(f[j]);
                l.u[j] = bf16_rne(f[j] - bf16_to_f(h.u[j]));
            }
            *(bf16x8*)(base + arow * 64 + aslot * 16)          = h.v;
            *(bf16x8*)(base + ABYTES + arow * 64 + aslot * 16) = l.v;
        }
    };

    const int NT = K / 32;

    // ---- prologue: fill buf0 (A via regs, B via DMA), preload pA = tile 1
    float4 pA0, pA1, nA0, nA1;
    loadA(pA0, pA1, 0);           // tile 0 (oldest VMEM)
    issueB(0, 0);                 // 8 DMAs/wave (a-waves: after the 2 loads)
    writeA(0, pA0, pA1);          // compiler waits the 2 A loads (vmcnt(8))
    if (NT > 1) loadA(pA0, pA1, 32);   // pA := tile 1
    wg_barrier_leave(awave && NT > 1); // drain DMAs + ds_writes, keep pA loads

    int cur = 0;
    for (int t = 0; t < NT; ++t) {
        const bool hasNext  = (t + 1 < NT);
        const bool hasNext2 = (t + 2 < NT);

        // phase 1: next-tile B DMAs, then tile-(t+2) A loads (NEWEST issues)
        if (hasNext)  issueB(cur ^ 1, (t + 1) * 32);
        if (hasNext2) loadA(nA0, nA1, (t + 2) * 32);

        // phase 2: compute tile t from buf[cur]
        const unsigned short* sAh = (const unsigned short*)(smem + cur * BUFBYTES);
        const unsigned short* sAl = (const unsigned short*)(smem + cur * BUFBYTES + ABYTES);
        const unsigned short* sBh = (const unsigned short*)(smem + cur * BUFBYTES + 2 * ABYTES);
        const unsigned short* sBl = (const unsigned short*)(smem + cur * BUFBYTES + 2 * ABYTES + BBYTES);

        bf16x8 ah[4], al[4], bh[4], bl[4];
#pragma unroll
        for (int mi = 0; mi < 4; ++mi) {
            int row = wm * 64 + mi * 16 + r15;
            int off = row * 32 + ((q ^ ((row >> 1) & 3)) * 8);
            ah[mi] = *(const bf16x8*)&sAh[off];
            al[mi] = *(const bf16x8*)&sAl[off];
        }
#pragma unroll
        for (int ni = 0; ni < 4; ++ni) {
            int row = wn * 64 + ni * 16 + r15;
            int off = row * 32 + ((q ^ ((row >> 1) & 3)) * 8);
            bh[ni] = *(const bf16x8*)&sBh[off];
            bl[ni] = *(const bf16x8*)&sBl[off];
        }

#pragma unroll
        for (int mi = 0; mi < 4; ++mi)
#pragma unroll
            for (int ni = 0; ni < 4; ++ni) {
                acc[mi][ni] = __builtin_amdgcn_mfma_f32_16x16x32_bf16(ah[mi], bh[ni], acc[mi][ni], 0, 0, 0);
                acc[mi][ni] = __builtin_amdgcn_mfma_f32_16x16x32_bf16(ah[mi], bl[ni], acc[mi][ni], 0, 0, 0);
                acc[mi][ni] = __builtin_amdgcn_mfma_f32_16x16x32_bf16(al[mi], bh[ni], acc[mi][ni], 0, 0, 0);
            }

        // phase 3: convert+write tile t+1 from pA (loaded one full iter ago)
        if (hasNext) { writeA(cur ^ 1, pA0, pA1); pA0 = nA0; pA1 = nA1; }

        // barrier: drain B DMAs + ds ops, keep the 2 newest (nA) in flight
        wg_barrier_leave(awave && hasNext2);
        cur ^= 1;
    }

    // ---- fused epilogue: logits -> LDS f32, block-wide gumbel-softmax ----
    float* sL = (float*)smem;
    constexpr int LSTR = BN + 1;   // pad to break bank conflicts
#pragma unroll
    for (int ni = 0; ni < 4; ++ni) {
        int col = wn * 64 + ni * 16 + r15;
        float bv = bias[n0 + col];
#pragma unroll
        for (int mi = 0; mi < 4; ++mi) {
            int rbase = wm * 64 + mi * 16 + q * 4;
#pragma unroll
            for (int rr = 0; rr < 4; ++rr)
                sL[(rbase + rr) * LSTR + col] = acc[mi][ni][rr] + bv;
        }
    }
    __syncthreads();

    // 2*BM row-groups (row, group), one wave each; 160 vals -> 3 per lane.
    // Software-pipelined: gumbel for rg+NW issued before reducing rg.
    const int RGTOT = 2 * BM;
    const bool has2 = (lane < VG - 128);   // lanes 0..31
    int rg = wid;
    float c0 = 0.f, c1 = 0.f, c2 = 0.f;
    if (rg < RGTOT) {
        const float* gs = gumbel + (size_t)(m0 + (rg >> 1)) * NVARS + (rg & 1) * VG;
        c0 = gs[lane]; c1 = gs[lane + 64];
        c2 = has2 ? gs[lane + 128] : 0.f;
    }
    for (; rg < RGTOT; rg += NW) {
        const int rgn = rg + NW;
        float n0g = 0.f, n1g = 0.f, n2g = 0.f;
        if (rgn < RGTOT) {
            const float* gs = gumbel + (size_t)(m0 + (rgn >> 1)) * NVARS + (rgn & 1) * VG;
            n0g = gs[lane]; n1g = gs[lane + 64];
            n2g = has2 ? gs[lane + 128] : 0.f;
        }

        const int r = rg >> 1, g = rg & 1;
        const float* lrow = sL + r * LSTR + g * VG;
        float y0 = (lrow[lane]       + c0) * 0.5f;   // /TEMP
        float y1 = (lrow[lane + 64]  + c1) * 0.5f;
        float y2 = has2 ? (lrow[lane + 128] + c2) * 0.5f : -3.402823466e+38f;

        float mx = fmaxf(fmaxf(y0, y1), y2);
#pragma unroll
        for (int off = 32; off > 0; off >>= 1)
            mx = fmaxf(mx, __shfl_xor(mx, off, 64));

        float e0 = expf(y0 - mx);
        float e1 = expf(y1 - mx);
        float e2 = has2 ? expf(y2 - mx) : 0.f;
        float s  = e0 + e1 + e2;
#pragma unroll
        for (int off = 32; off > 0; off >>= 1)
            s += __shfl_xor(s, off, 64);
        const float inv = 1.0f / s;

        float* prow = probs + (size_t)(m0 + r) * NVARS + g * VG;
        prow[lane]      = e0 * inv;
        prow[lane + 64] = e1 * inv;
        if (has2) prow[lane + 128] = e2 * inv;

        // argmax over y (monotone-equivalent to argmax over probs),
        // first-occurrence tie-break — identical to previous rounds
        float bvv = y0; int bii = lane;
        if (y1 > bvv) { bvv = y1; bii = lane + 64; }
        if (has2 && y2 > bvv) { bvv = y2; bii = lane + 128; }
#pragma unroll
        for (int off = 32; off > 0; off >>= 1) {
            float ov = __shfl_xor(bvv, off, 64);
            int   oi = __shfl_xor(bii, off, 64);
            if (ov > bvv || (ov == bvv && oi < bii)) { bvv = ov; bii = oi; }
        }
        if (lane == 0) codes[(size_t)(m0 + r) * NGROUPS + g] = (float)bii;

        c0 = n0g; c1 = n1g; c2 = n2g;
    }
}

// ===========================================================================
// FUSED GEMM2 (R5): quantized = probs(fp32) @ (CBhi+CBlo), same counted-
// vmcnt pipeline as GEMM1 (A = probs is L3-hot; 2-deep reg prefetch + T14
// write-late convert).  Instantiated <128, 384, 2, 6> (768 thr, grid (2,384)).
// ===========================================================================
template<int BM, int BN, int WM, int WN>
__global__ __launch_bounds__(WM*WN*64, (WM*WN+3)/4)
void gemm2_fused(const float* __restrict__ P,
                 const unsigned short* __restrict__ Bthi,
                 const unsigned short* __restrict__ Btlo,
                 float* __restrict__ C,
                 int M, int N, int K)
{
    constexpr int NW = WM * WN;
    constexpr int ACH    = BM * 4;
    constexpr int AW     = ACH / 64;
    constexpr int nIterB = (BN * 4) / 64;
    constexpr int ABYTES = BM * 32 * 2;
    constexpr int BBYTES = BN * 32 * 2;
    constexpr int BUFBYTES = 2 * ABYTES + 2 * BBYTES;

    extern __shared__ __align__(16) char smem[];   // 2 * BUFBYTES

    const int tid  = threadIdx.x;
    const int lane = tid & 63;
    const int wid  = tid >> 6;
    const int wm   = wid % WM;
    const int wn   = wid / WM;
    const int m0   = blockIdx.y * BM;
    const int n0   = blockIdx.x * BN;

    const int r15 = lane & 15;
    const int q   = lane >> 4;

    const int arow  = tid >> 2;
    const int ac    = tid & 3;
    const int aslot = ac ^ ((arow >> 1) & 3);
    const float* aptr = P + (size_t)(m0 + arow) * K + ac * 8;
    const bool adoes = (tid < ACH);
    const bool awave = (wid < AW);

    f32x4 acc[4][4];
#pragma unroll
    for (int i = 0; i < 4; ++i)
#pragma unroll
        for (int j = 0; j < 4; ++j) {
            f32x4 z = {0.f, 0.f, 0.f, 0.f};
            acc[i][j] = z;
        }

    auto issueB = [&](int buf, int k0) {
        char* base = smem + buf * BUFBYTES + 2 * ABYTES;
        for (int i = wid; i < nIterB; i += NW) {
            int slot = i * 64 + lane;
            int row  = slot >> 2, cs = slot & 3;
            int c    = cs ^ ((row >> 1) & 3);
            size_t goff = (size_t)(n0 + row) * K + k0 + c * 8;
            gl2lds16(Bthi + goff, base + i * 1024);
            gl2lds16(Btlo + goff, base + BBYTES + i * 1024);
        }
    };
    auto loadA = [&](float4& v0, float4& v1, int k0) {
        if (adoes) {
            v0 = *(const float4*)(aptr + k0);
            v1 = *(const float4*)(aptr + k0 + 4);
        }
    };
    auto writeA = [&](int buf, float4 v0, float4 v1) {
        if (adoes) {
            char* base = smem + buf * BUFBYTES;
            union { unsigned short u[8]; bf16x8 v; } h, l;
            float f[8] = {v0.x, v0.y, v0.z, v0.w, v1.x, v1.y, v1.z, v1.w};
#pragma unroll
            for (int j = 0; j < 8; ++j) {
                h.u[j] = bf16_rne(f[j]);
                l.u[j] = bf16_rne(f[j] - bf16_to_f(h.u[j]));
            }
            *(bf16x8*)(base + arow * 64 + aslot * 16)          = h.v;
            *(bf16x8*)(base + ABYTES + arow * 64 + aslot * 16) = l.v;
        }
    };

    const int NT = K / 32;

    float4 pA0, pA1, nA0, nA1;
    loadA(pA0, pA1, 0);
    issueB(0, 0);
    writeA(0, pA0, pA1);
    if (NT > 1) loadA(pA0, pA1, 32);
    wg_barrier_leave(awave && NT > 1);

    int cur = 0;
    for (int t = 0; t < NT; ++t) {
        const bool hasNext  = (t + 1 < NT);
        const bool hasNext2 = (t + 2 < NT);

        if (hasNext)  issueB(cur ^ 1, (t + 1) * 32);
        if (hasNext2) loadA(nA0, nA1, (t + 2) * 32);

        const unsigned short* sAh = (const unsigned short*)(smem + cur * BUFBYTES);
        const unsigned short* sAl = (const unsigned short*)(smem + cur * BUFBYTES + ABYTES);
        const unsigned short* sBh = (const unsigned short*)(smem + cur * BUFBYTES + 2 * ABYTES);
        const unsigned short* sBl = (const unsigned short*)(smem + cur * BUFBYTES + 2 * ABYTES + BBYTES);

        bf16x8 ah[4], al[4], bh[4], bl[4];
#pragma unroll
        for (int mi = 0; mi < 4; ++mi) {
            int row = wm * 64 + mi * 16 + r15;
            int off = row * 32 + ((q ^ ((row >> 1) & 3)) * 8);
            ah[mi] = *(const bf16x8*)&sAh[off];
            al[mi] = *(const bf16x8*)&sAl[off];
        }
#pragma unroll
        for (int ni = 0; ni < 4; ++ni) {
            int row = wn * 64 + ni * 16 + r15;
            int off = row * 32 + ((q ^ ((row >> 1) & 3)) * 8);
            bh[ni] = *(const bf16x8*)&sBh[off];
            bl[ni] = *(const bf16x8*)&sBl[off];
        }

#pragma unroll
        for (int mi = 0; mi < 4; ++mi)
#pragma unroll
            for (int ni = 0; ni < 4; ++ni) {
                acc[mi][ni] = __builtin_amdgcn_mfma_f32_16x16x32_bf16(ah[mi], bh[ni], acc[mi][ni], 0, 0, 0);
                acc[mi][ni] = __builtin_amdgcn_mfma_f32_16x16x32_bf16(ah[mi], bl[ni], acc[mi][ni], 0, 0, 0);
                acc[mi][ni] = __builtin_amdgcn_mfma_f32_16x16x32_bf16(al[mi], bh[ni], acc[mi][ni], 0, 0, 0);
            }

        if (hasNext) { writeA(cur ^ 1, pA0, pA1); pA0 = nA0; pA1 = nA1; }

        wg_barrier_leave(awave && hasNext2);
        cur ^= 1;
    }

    // epilogue: C/D layout col=lane&15, row=quad*4+reg (m89/m91-verified)
#pragma unroll
    for (int ni = 0; ni < 4; ++ni) {
        int col = n0 + wn * 64 + ni * 16 + r15;
#pragma unroll
        for (int mi = 0; mi < 4; ++mi) {
            int rbase = m0 + wm * 64 + mi * 16 + q * 4;
#pragma unroll
            for (int rr = 0; rr < 4; ++rr)
                C[(size_t)(rbase + rr) * N + col] = acc[mi][ni][rr];
        }
    }
}

// ---------------------------------------------------------------------------
// Fallback kernels (known-good fp32 path) if ws is too small.
// ---------------------------------------------------------------------------
__global__ __launch_bounds__(256)
void gumbel_softmax_kernel(float* __restrict__ logits_probs,
                           const float* __restrict__ gumbel,
                           float* __restrict__ codes,
                           unsigned short* __restrict__ phi,
                           unsigned short* __restrict__ plo)
{
    const int wid  = (int)((blockIdx.x * (size_t)blockDim.x + threadIdx.x) >> 6);
    const int lane = threadIdx.x & 63;
    if (wid >= BT_TOK * NGROUPS) return;

    float* base        = logits_probs + (size_t)wid * VG;
    const float* gbase = gumbel       + (size_t)wid * VG;

    const float NEG = -3.402823466e+38f;
    float y[3];
    float mx = NEG;
#pragma unroll
    for (int i = 0; i < 3; ++i) {
        int v = lane + i * 64;
        float val = NEG;
        if (v < VG) val = (base[v] + gbase[v]) * 0.5f;
        y[i] = val;
        mx = fmaxf(mx, val);
    }
#pragma unroll
    for (int off = 32; off > 0; off >>= 1)
        mx = fmaxf(mx, __shfl_xor(mx, off, 64));

    float e[3];
    float s = 0.f;
#pragma unroll
    for (int i = 0; i < 3; ++i) {
        int v = lane + i * 64;
        e[i] = (v < VG) ? expf(y[i] - mx) : 0.f;
        s += e[i];
    }
#pragma unroll
    for (int off = 32; off > 0; off >>= 1)
        s += __shfl_xor(s, off, 64);
    const float inv = 1.0f / s;

#pragma unroll
    for (int i = 0; i < 3; ++i) {
        int v = lane + i * 64;
        if (v < VG) {
            float p = e[i] * inv;
            base[v] = p;
            if (phi) {
                unsigned short h = bf16_rne(p);
                phi[(size_t)wid * VG + v] = h;
                plo[(size_t)wid * VG + v] = bf16_rne(p - bf16_to_f(h));
            }
        }
    }

    float bv = y[0];
    int   bi = lane;
#pragma unroll
    for (int i = 1; i < 3; ++i) {
        int v = lane + i * 64;
        if (v < VG && y[i] > bv) { bv = y[i]; bi = v; }
    }
#pragma unroll
    for (int off = 32; off > 0; off >>= 1) {
        float ov = __shfl_xor(bv, off, 64);
        int   oi = __shfl_xor(bi, off, 64);
        if (ov > bv || (ov == bv && oi < bi)) { bv = ov; bi = oi; }
    }
    if (lane == 0) codes[wid] = (float)bi;
}

__global__ __launch_bounds__(256)
void sgemm64(const float* __restrict__ A, const float* __restrict__ B,
             const float* __restrict__ bias, float* __restrict__ C,
             int M, int N, int K)
{
    const int tid = threadIdx.x;
    const int n0  = blockIdx.x * 64;
    const int m0  = blockIdx.y * 64;

    __shared__ float As[16][64 + 4];
    __shared__ float Bs[16][64];

    const int a_row = tid >> 2;
    const int a_k   = (tid & 3) * 4;
    const int b_row = tid >> 4;
    const int b_col = (tid & 15) * 4;
    const int tx = tid & 15;
    const int ty = tid >> 4;

    float acc[4][4] = {};

    for (int k0 = 0; k0 < K; k0 += 16) {
        float4 av = *(const float4*)(A + (size_t)(m0 + a_row) * K + k0 + a_k);
        float4 bv = *(const float4*)(B + (size_t)(k0 + b_row) * N + n0 + b_col);
        __syncthreads();
        As[a_k + 0][a_row] = av.x;
        As[a_k + 1][a_row] = av.y;
        As[a_k + 2][a_row] = av.z;
        As[a_k + 3][a_row] = av.w;
        *(float4*)&Bs[b_row][b_col] = bv;
        __syncthreads();
#pragma unroll
        for (int k = 0; k < 16; ++k) {
            float4 a4 = *(const float4*)&As[k][ty * 4];
            float4 b4 = *(const float4*)&Bs[k][tx * 4];
            const float a[4] = {a4.x, a4.y, a4.z, a4.w};
            const float b[4] = {b4.x, b4.y, b4.z, b4.w};
#pragma unroll
            for (int r = 0; r < 4; ++r)
#pragma unroll
                for (int c = 0; c < 4; ++c)
                    acc[r][c] = fmaf(a[r], b[c], acc[r][c]);
        }
    }

    float4 bs = make_float4(0.f, 0.f, 0.f, 0.f);
    if (bias) bs = *(const float4*)(bias + n0 + tx * 4);
#pragma unroll
    for (int r = 0; r < 4; ++r) {
        float4 o;
        o.x = acc[r][0] + bs.x;
        o.y = acc[r][1] + bs.y;
        o.z = acc[r][2] + bs.z;
        o.w = acc[r][3] + bs.w;
        *(float4*)(C + (size_t)(m0 + ty * 4 + r) * N + n0 + tx * 4) = o;
    }
}

// ---------------------------------------------------------------------------
extern "C" void kernel_launch(void* const* d_in, const int* in_sizes, int n_in,
                              void* d_out, int out_size, void* d_ws, size_t ws_size,
                              hipStream_t stream) {
    const float* x        = (const float*)d_in[0];   // (BT, 768)
    const float* gumbel   = (const float*)d_in[1];   // (BT, 320)
    const float* W_proj   = (const float*)d_in[2];   // (768, 320)
    const float* b_proj   = (const float*)d_in[3];   // (320,)
    const float* codebook = (const float*)d_in[4];   // (320, 768)

    float* quantized = (float*)d_out;
    float* codes     = quantized + (size_t)BT_TOK * C_DIM;
    float* probs     = codes + (size_t)BT_TOK * NGROUPS;

    // workspace: only the two transposed weight matrices (hi/lo) now
    const size_t SZ_W  = (size_t)C_DIM * NVARS * 2;    // 491,520 per buffer
    const size_t need  = 4 * SZ_W;                     // ~2 MB

    // dynamic-LDS sizes
    constexpr int SH1 = 2 * (2 * (64 * 32 * 2)  + 2 * (320 * 32 * 2));   //  98304 B
    constexpr int SH2 = 2 * (2 * (128 * 32 * 2) + 2 * (384 * 32 * 2));   // 131072 B

    if (ws_size >= need) {
        static bool s_init = false;
        if (!s_init) {
            hipFuncSetAttribute(reinterpret_cast<const void*>(&gemm1_softmax_fused<64, 320, 1, 5>),
                                hipFuncAttributeMaxDynamicSharedMemorySize, SH1);
            hipFuncSetAttribute(reinterpret_cast<const void*>(&gemm2_fused<128, 384, 2, 6>),
                                hipFuncAttributeMaxDynamicSharedMemorySize, SH2);
            s_init = true;
        }

        char* ws = (char*)d_ws;
        unsigned short* wthi = (unsigned short*)(ws);
        unsigned short* wtlo = (unsigned short*)(ws + SZ_W);
        unsigned short* cthi = (unsigned short*)(ws + 2 * SZ_W);
        unsigned short* ctlo = (unsigned short*)(ws + 3 * SZ_W);

        // tiny weight prepasses
        transpose_split<<<dim3((C_DIM + 255) / 256, NVARS), 256, 0, stream>>>(
            W_proj, wthi, wtlo, C_DIM, NVARS);
        transpose_split<<<dim3((NVARS + 255) / 256, C_DIM), 256, 0, stream>>>(
            codebook, cthi, ctlo, NVARS, C_DIM);

        // fused GEMM1 + softmax: x -> probs, codes (logits stay on-chip)
        gemm1_softmax_fused<64, 320, 1, 5><<<dim3(1, BT_TOK / 64), 320, SH1, stream>>>(
            x, wthi, wtlo, b_proj, gumbel, probs, codes, BT_TOK, NVARS, C_DIM);

        // fused GEMM2: probs (fp32, split in-register) @ codebook -> quantized
        gemm2_fused<128, 384, 2, 6><<<dim3(C_DIM / 384, BT_TOK / 128), 768, SH2, stream>>>(
            probs, cthi, ctlo, quantized, BT_TOK, C_DIM, NVARS);
    } else {
        // fallback: known-good fp32 path
        dim3 g1(NVARS / 64, BT_TOK / 64);
        sgemm64<<<g1, 256, 0, stream>>>(x, W_proj, b_proj, probs, BT_TOK, NVARS, C_DIM);
        gumbel_softmax_kernel<<<BT_TOK * NGROUPS / 4, 256, 0, stream>>>(
            probs, gumbel, codes, nullptr, nullptr);
        dim3 g2(C_DIM / 64, BT_TOK / 64);
        sgemm64<<<g2, 256, 0, stream>>>(probs, codebook, nullptr, quantized, BT_TOK, C_DIM, NVARS);
    }
}